// Round 10
// baseline (239.200 us; speedup 1.0000x reference)
//
#include <hip/hip_runtime.h>

#define DCH 128
#define ROWS 16
#define BN_EPS 1e-5f

typedef unsigned short u16;
typedef __attribute__((ext_vector_type(8))) short short8;
typedef __attribute__((ext_vector_type(4))) float floatx4;
typedef __attribute__((ext_vector_type(2))) unsigned uint2v;

__device__ __forceinline__ float bf2f(u16 u) {
    return __uint_as_float(((unsigned)u) << 16);
}
__device__ __forceinline__ u16 f2bf(float f) {
    unsigned u = __float_as_uint(f);
    u += 0x7FFFu + ((u >> 16) & 1u);   // RNE, finite inputs
    return (u16)(u >> 16);
}
__device__ __forceinline__ float ldf(const void* p, int i, int isbf) {
    return isbf ? bf2f(((const u16*)p)[i]) : ((const float*)p)[i];
}

__global__ void zero_kernel(float* p, int n) {
    int stride = gridDim.x * 256;
    for (int i = blockIdx.x * 256 + threadIdx.x; i < n; i += stride) p[i] = 0.f;
}

__global__ void paint_kernel(u16* out, int n, unsigned val) {
    int stride = gridDim.x * 256;
    for (int i = blockIdx.x * 256 + threadIdx.x; i < n; i += stride) out[i] = (u16)val;
}

// ws_i[0]=edge-is-int64  ws_i[1]=floats-are-bf16  ws_i[2]=errbits
// Workspace head pre-zeroed by zero_kernel (R5 lesson: NOT host memset — it
// failed under graph capture, leaving deg garbage -> OOB col writes).
// Every block recomputes is64/isbf locally from the same leading bytes
// (deterministic), packs a slice of W, and counts a degree slice.
// R9: int64 fast path reads only the DEST half of ei (src bounds-check was
// diagnostic-only; fillcsr clamps src anyway) — halves prep's edge traffic.
__global__ void prep_deg_kernel(const int* ei, int E, const u16* xw, int* ws_i,
                                const void* W, u16* Wb, int* deg, int N) {
    int t = threadIdx.x;
    __shared__ int s_nz, s_hits;
    if (t == 0) { s_nz = 0; s_hits = 0; }
    __syncthreads();
    int ewords = 2 * E;
    int nz = 0;
    for (int i = t; i < 1024; i += 256) {
        int w = 2 * i + 1;
        if (w < ewords) nz |= ei[w];
    }
    if (nz) atomicOr(&s_nz, 1);
    unsigned m = (xw[2 * t] >> 8) & 0x7F;
    if (m >= 0x3B && m <= 0x43) atomicAdd(&s_hits, 1);
    __syncthreads();
    int is64 = (s_nz == 0) ? 1 : 0;
    int isbf = (s_hits >= 128) ? 1 : 0;
    if (blockIdx.x == 0 && t == 0) {
        ws_i[0] = is64;
        ws_i[1] = isbf;
        // ws_i[2] (errbits) pre-zeroed; other blocks may atomicOr it now.
    }
    int gid = blockIdx.x * 256 + t;
    int gthreads = gridDim.x * 256;
    // pack W: Wb[((nt*4+kk)*64+lane)*8+j] = bf16(W[(kk*32+(lane>>4)*8+j)*128 + nt*16+(lane&15)])
    for (int idx = gid; idx < DCH * DCH; idx += gthreads) {
        int j = idx & 7, lane = (idx >> 3) & 63, kk = (idx >> 9) & 3, nt = idx >> 11;
        int k = kk * 32 + (lane >> 4) * 8 + j;
        int n = nt * 16 + (lane & 15);
        Wb[idx] = f2bf(ldf(W, k * DCH + n, isbf));
    }
    // degree count
    if (is64 && !(E & 1)) {
        int P2 = E >> 1;
        for (int p = gid; p < P2; p += gthreads) {
            int4 dp = ((const int4*)(ei + 2 * E))[p];
            if (((unsigned)dp.x >= (unsigned)N) || ((unsigned)dp.z >= (unsigned)N))
                atomicOr(&ws_i[2], 2);
            atomicAdd(&deg[min(max(dp.x, 0), N - 1)], 1);
            atomicAdd(&deg[min(max(dp.z, 0), N - 1)], 1);
        }
    } else {
        for (int e = gid; e < E; e += gthreads) {
            int s = is64 ? ei[2 * e] : ei[e];
            int d = is64 ? ei[2 * E + 2 * e] : ei[E + e];
            if (((unsigned)s >= (unsigned)N) || ((unsigned)d >= (unsigned)N))
                atomicOr(&ws_i[2], 2);
            atomicAdd(&deg[min(max(d, 0), N - 1)], 1);
        }
    }
}

__global__ void detect_kernel(const int* ei, int ewords, const u16* xw, int* ws_i) {
    __shared__ int s_nz, s_hits;
    int t = threadIdx.x;
    if (t == 0) { s_nz = 0; s_hits = 0; }
    __syncthreads();
    int nz = 0;
    for (int i = t; i < 1024; i += 256) {
        int w = 2 * i + 1;
        if (w < ewords) nz |= ei[w];
    }
    if (nz) atomicOr(&s_nz, 1);
    unsigned m = (xw[2 * t] >> 8) & 0x7F;
    if (m >= 0x3B && m <= 0x43) atomicAdd(&s_hits, 1);
    __syncthreads();
    if (t == 0) {
        ws_i[0] = (s_nz == 0) ? 1 : 0;
        ws_i[1] = (s_hits >= 128) ? 1 : 0;
        ws_i[2] = 0;
    }
}

__global__ void deg_kernel(const int* ei, int E, int* ws_i, int* deg, int N) {
    int is64 = ws_i[0];
    int i = blockIdx.x * 256 + threadIdx.x;
    if (i < E) {
        int s = is64 ? ei[2 * i] : ei[i];
        int d = is64 ? ei[2 * E + 2 * i] : ei[E + i];
        if (((unsigned)s >= (unsigned)N) || ((unsigned)d >= (unsigned)N))
            atomicOr(&ws_i[2], 2);
        d = min(max(d, 0), N - 1);
        atomicAdd(&deg[d], 1);
    }
}

__global__ void dinv_kernel(const int* deg, float* dinv, int N, int* ws_i) {
    int i = blockIdx.x * 256 + threadIdx.x;
    if (i < N) {
        float v = rsqrtf((float)(deg[i] + 1));
        if (!(v > 0.f && v <= 1.001f)) atomicOr(&ws_i[2], 4);
        dinv[i] = v;
    }
}

// ---- scan of deg -> rowptr (R6-proven coalesced pair; R7 lesson: the
// single-block scan1 had per-thread-contiguous = per-wave-strided reads ->
// 64 cache lines per load, 147us on one CU. Coalesced grid-parallel wins.)
__global__ void scanA_kernel(const int* deg, int* part, int N) {
    int base = blockIdx.x * 1024 + threadIdx.x * 4;
    int s = 0;
    #pragma unroll
    for (int j = 0; j < 4; ++j) {
        int i = base + j;
        if (i < N) s += deg[i];
    }
    #pragma unroll
    for (int o = 1; o < 64; o <<= 1) s += __shfl_xor(s, o, 64);
    __shared__ int ws4[4];
    if ((threadIdx.x & 63) == 0) ws4[threadIdx.x >> 6] = s;
    __syncthreads();
    if (threadIdx.x == 0) part[blockIdx.x] = ws4[0] + ws4[1] + ws4[2] + ws4[3];
}

__global__ void scanC_kernel(int* deg_cursor, const int* part, int* rowptr,
                             float* dinv, int N, int P) {
    __shared__ int wsum[4], wsP[4];
    int t = threadIdx.x, lane = t & 63, w = t >> 6;
    // local exclusive base: sum part[j] for j < blockIdx.x  (raw block sums, P<=256)
    int pv = (t < P && t < (int)blockIdx.x) ? part[t] : 0;
    #pragma unroll
    for (int o = 1; o < 64; o <<= 1) pv += __shfl_xor(pv, o, 64);
    if (lane == 0) wsP[w] = pv;

    int base = blockIdx.x * 1024 + t * 4;
    int v[4], ts = 0;
    #pragma unroll
    for (int j = 0; j < 4; ++j) {
        int i = base + j;
        v[j] = (i < N) ? deg_cursor[i] : 0;
        ts += v[j];
    }
    int sc = ts;
    #pragma unroll
    for (int o = 1; o < 64; o <<= 1) {
        int u = __shfl_up(sc, o, 64);
        if (lane >= o) sc += u;
    }
    if (lane == 63) wsum[w] = sc;
    __syncthreads();
    if (t < 4) {
        int s = wsum[t];
        #pragma unroll
        for (int o = 1; o < 4; o <<= 1) {
            int u = __shfl_up(s, o, 4);
            if (t >= o) s += u;
        }
        wsum[t] = s;
    }
    __syncthreads();
    int blockbase = wsP[0] + wsP[1] + wsP[2] + wsP[3];
    int run = sc - ts + (w ? wsum[w - 1] : 0) + blockbase;
    #pragma unroll
    for (int j = 0; j < 4; ++j) {
        int i = base + j;
        if (i < N) {
            deg_cursor[i] = run;                       // exclusive (cursor start)
            run += v[j];
            rowptr[i + 1] = run;                       // inclusive
            dinv[i] = rsqrtf((float)(v[j] + 1));       // fused dinv
        }
    }
    if (blockIdx.x == 0 && t == 0) rowptr[0] = 0;
}
// ------------------------------------------------------------------

// Fused: blocks [0,GB) run the MFMA GEMM (proven body), blocks [GB,..) run
// fillcsr (proven body). Both depend only on the scan (cursor/dinv) and are
// resource-disjoint (MFMA+stores vs atomics) -> one dispatch, real overlap.
__global__ void fill_gemm_kernel(const int* ei, int E, const int* ws_i,
                                 int* cursor, int* col,
                                 const void* x, const u16* Wb, const float* dinv,
                                 u16* y, int N, int GB) {
    int t = threadIdx.x;
    if ((int)blockIdx.x < GB) {
        // ---- GEMM body (verbatim) ----
        int isbf = ws_i[1];
        int wv = t >> 6, lane = t & 63;
        int quad = lane >> 4, l16 = lane & 15;
        int r0 = blockIdx.x * 64 + wv * 16;
        int rl = min(r0 + l16, N - 1);
        short8 a[4];
        if (isbf) {
            const u16* xp = (const u16*)x + (size_t)rl * DCH + quad * 8;
            #pragma unroll
            for (int kk = 0; kk < 4; ++kk)
                a[kk] = *(const short8*)(xp + kk * 32);
        } else {
            const float* xp = (const float*)x + (size_t)rl * DCH + quad * 8;
            #pragma unroll
            for (int kk = 0; kk < 4; ++kk) {
                float4 f0 = *(const float4*)(xp + kk * 32);
                float4 f1 = *(const float4*)(xp + kk * 32 + 4);
                short8 aa;
                aa[0] = (short)f2bf(f0.x); aa[1] = (short)f2bf(f0.y);
                aa[2] = (short)f2bf(f0.z); aa[3] = (short)f2bf(f0.w);
                aa[4] = (short)f2bf(f1.x); aa[5] = (short)f2bf(f1.y);
                aa[6] = (short)f2bf(f1.z); aa[7] = (short)f2bf(f1.w);
                a[kk] = aa;
            }
        }
        floatx4 acc[8];
        #pragma unroll
        for (int i = 0; i < 8; ++i) acc[i] = (floatx4)(0.f);
        #pragma unroll
        for (int nt = 0; nt < 8; ++nt) {
            #pragma unroll
            for (int kk = 0; kk < 4; ++kk) {
                short8 bfr = *(const short8*)&Wb[(((nt << 2) | kk) * 64 + lane) * 8];
                acc[nt] = __builtin_amdgcn_mfma_f32_16x16x32_bf16(a[kk], bfr, acc[nt], 0, 0, 0);
            }
        }
        #pragma unroll
        for (int i = 0; i < 4; ++i) {
            int row = r0 + quad * 4 + i;
            if (row < N) {
                float dv = dinv[row];
                #pragma unroll
                for (int nt = 0; nt < 8; ++nt)
                    y[(size_t)row * DCH + nt * 16 + l16] = f2bf(acc[nt][i] * dv);
            }
        }
    } else {
        // ---- fillcsr body (verbatim, block index shifted) ----
        int is64 = ws_i[0];
        int i = (blockIdx.x - GB) * 256 + t;
        if (is64 && !(E & 1)) {
            if (2 * i < E) {
                int4 sp = ((const int4*)ei)[i];
                int4 dp = ((const int4*)(ei + 2 * E))[i];
                int s0 = min(max(sp.x, 0), N - 1), d0 = min(max(dp.x, 0), N - 1);
                int s1 = min(max(sp.z, 0), N - 1), d1 = min(max(dp.z, 0), N - 1);
                int p0 = atomicAdd(&cursor[d0], 1);
                if ((unsigned)p0 < (unsigned)E) col[p0] = s0;   // defensive bound
                int p1 = atomicAdd(&cursor[d1], 1);
                if ((unsigned)p1 < (unsigned)E) col[p1] = s1;
            }
        } else if (i < E) {
            int s = is64 ? ei[2 * i] : ei[i];
            int d = is64 ? ei[2 * E + 2 * i] : ei[E + i];
            s = min(max(s, 0), N - 1);
            d = min(max(d, 0), N - 1);
            int pos = atomicAdd(&cursor[d], 1);
            if ((unsigned)pos < (unsigned)E) col[pos] = s;
        }
    }
}

// gather + BN-stats fused. Half-wave per node, lane owns 4 channels (uint2v 8B
// loads). R9/R10: 512 blocks (4096 streams). Stream-count curve: 8192 streams
// -> 68MB fetch/59.5us; 16384 -> 94MB/77.9us (R1). Traffic scales with stream
// count (L2 reuse window); concurrency stays above the Little's-law threshold
// (4096x8x8 = 32K outstanding > ~17.5K needed at 1.6TB/s x 700ns), and R2
// showed per-stream MLP is not the binding constraint. Deep per-stream
// pipeline: 8 y-gathers in flight, col prefetched a group ahead, next node's
// rowptr+self-row prefetched. h store + col loads nontemporal.
__global__ __launch_bounds__(256, 4)
void gather_stats_kernel(const int* rowptr, const int* col, const u16* y,
                         const float* dinv, const void* b, const int* ws_i,
                         float* h, float* sums, float* sumsq, int N) {
    int isbf = ws_i[1];
    int t = threadIdx.x;
    int hw = t >> 5;                 // half-wave id in block [0,8)
    int l32 = t & 31;
    int c0 = l32 * 4;
    float bb[4];
    #pragma unroll
    for (int k = 0; k < 4; ++k) bb[k] = ldf(b, c0 + k, isbf);
    float ps[4] = {0.f, 0.f, 0.f, 0.f}, pq[4] = {0.f, 0.f, 0.f, 0.f};
    int stream_id = blockIdx.x * 8 + hw;
    int nstreams = gridDim.x * 8;

    int n = stream_id;
    int beg = 0, end = 0;
    uint2v qs = (uint2v)(0u);
    if (n < N) {
        beg = rowptr[n];
        end = rowptr[n + 1];
        qs = *(const uint2v*)&y[(size_t)n * DCH + c0];
    }
    while (n < N) {
        // prefetch next node's rowptr + self-row while this node's edges stream
        int n2 = n + nstreams;
        int begN = 0, endN = 0;
        uint2v qsN = (uint2v)(0u);
        if (n2 < N) {
            begN = rowptr[n2];
            endN = rowptr[n2 + 1];
            qsN = *(const uint2v*)&y[(size_t)n2 * DCH + c0];
        }

        float a0[4] = { bf2f((u16)(qs.x & 0xFFFF)), bf2f((u16)(qs.x >> 16)),
                        bf2f((u16)(qs.y & 0xFFFF)), bf2f((u16)(qs.y >> 16)) };
        float a1[4] = {0.f, 0.f, 0.f, 0.f};
        float a2[4] = {0.f, 0.f, 0.f, 0.f};
        float a3[4] = {0.f, 0.f, 0.f, 0.f};
        int j = beg;
        int s0 = 0, s1 = 0, s2 = 0, s3 = 0, s4 = 0, s5 = 0, s6 = 0, s7 = 0;
        bool have8 = (j + 7 < end);
        if (have8) {
            s0 = __builtin_nontemporal_load(col + j);
            s1 = __builtin_nontemporal_load(col + j + 1);
            s2 = __builtin_nontemporal_load(col + j + 2);
            s3 = __builtin_nontemporal_load(col + j + 3);
            s4 = __builtin_nontemporal_load(col + j + 4);
            s5 = __builtin_nontemporal_load(col + j + 5);
            s6 = __builtin_nontemporal_load(col + j + 6);
            s7 = __builtin_nontemporal_load(col + j + 7);
        }
        while (have8) {
            // 8 independent y-row gathers in flight
            uint2v q0 = *(const uint2v*)&y[(size_t)s0 * DCH + c0];
            uint2v q1 = *(const uint2v*)&y[(size_t)s1 * DCH + c0];
            uint2v q2 = *(const uint2v*)&y[(size_t)s2 * DCH + c0];
            uint2v q3 = *(const uint2v*)&y[(size_t)s3 * DCH + c0];
            uint2v q4 = *(const uint2v*)&y[(size_t)s4 * DCH + c0];
            uint2v q5 = *(const uint2v*)&y[(size_t)s5 * DCH + c0];
            uint2v q6 = *(const uint2v*)&y[(size_t)s6 * DCH + c0];
            uint2v q7 = *(const uint2v*)&y[(size_t)s7 * DCH + c0];
            // prefetch next group's col indices before stalling on q0..q7
            int jn = j + 8;
            bool haven = (jn + 7 < end);
            if (haven) {
                s0 = __builtin_nontemporal_load(col + jn);
                s1 = __builtin_nontemporal_load(col + jn + 1);
                s2 = __builtin_nontemporal_load(col + jn + 2);
                s3 = __builtin_nontemporal_load(col + jn + 3);
                s4 = __builtin_nontemporal_load(col + jn + 4);
                s5 = __builtin_nontemporal_load(col + jn + 5);
                s6 = __builtin_nontemporal_load(col + jn + 6);
                s7 = __builtin_nontemporal_load(col + jn + 7);
            }
            a0[0] += bf2f((u16)(q0.x & 0xFFFF)); a0[1] += bf2f((u16)(q0.x >> 16));
            a0[2] += bf2f((u16)(q0.y & 0xFFFF)); a0[3] += bf2f((u16)(q0.y >> 16));
            a1[0] += bf2f((u16)(q1.x & 0xFFFF)); a1[1] += bf2f((u16)(q1.x >> 16));
            a1[2] += bf2f((u16)(q1.y & 0xFFFF)); a1[3] += bf2f((u16)(q1.y >> 16));
            a2[0] += bf2f((u16)(q2.x & 0xFFFF)); a2[1] += bf2f((u16)(q2.x >> 16));
            a2[2] += bf2f((u16)(q2.y & 0xFFFF)); a2[3] += bf2f((u16)(q2.y >> 16));
            a3[0] += bf2f((u16)(q3.x & 0xFFFF)); a3[1] += bf2f((u16)(q3.x >> 16));
            a3[2] += bf2f((u16)(q3.y & 0xFFFF)); a3[3] += bf2f((u16)(q3.y >> 16));
            a0[0] += bf2f((u16)(q4.x & 0xFFFF)); a0[1] += bf2f((u16)(q4.x >> 16));
            a0[2] += bf2f((u16)(q4.y & 0xFFFF)); a0[3] += bf2f((u16)(q4.y >> 16));
            a1[0] += bf2f((u16)(q5.x & 0xFFFF)); a1[1] += bf2f((u16)(q5.x >> 16));
            a1[2] += bf2f((u16)(q5.y & 0xFFFF)); a1[3] += bf2f((u16)(q5.y >> 16));
            a2[0] += bf2f((u16)(q6.x & 0xFFFF)); a2[1] += bf2f((u16)(q6.x >> 16));
            a2[2] += bf2f((u16)(q6.y & 0xFFFF)); a2[3] += bf2f((u16)(q6.y >> 16));
            a3[0] += bf2f((u16)(q7.x & 0xFFFF)); a3[1] += bf2f((u16)(q7.x >> 16));
            a3[2] += bf2f((u16)(q7.y & 0xFFFF)); a3[3] += bf2f((u16)(q7.y >> 16));
            j = jn; have8 = haven;
        }
        if (j + 3 < end) {            // at most one 4-group after the 8-loop
            s0 = __builtin_nontemporal_load(col + j);
            s1 = __builtin_nontemporal_load(col + j + 1);
            s2 = __builtin_nontemporal_load(col + j + 2);
            s3 = __builtin_nontemporal_load(col + j + 3);
            uint2v q0 = *(const uint2v*)&y[(size_t)s0 * DCH + c0];
            uint2v q1 = *(const uint2v*)&y[(size_t)s1 * DCH + c0];
            uint2v q2 = *(const uint2v*)&y[(size_t)s2 * DCH + c0];
            uint2v q3 = *(const uint2v*)&y[(size_t)s3 * DCH + c0];
            a0[0] += bf2f((u16)(q0.x & 0xFFFF)); a0[1] += bf2f((u16)(q0.x >> 16));
            a0[2] += bf2f((u16)(q0.y & 0xFFFF)); a0[3] += bf2f((u16)(q0.y >> 16));
            a1[0] += bf2f((u16)(q1.x & 0xFFFF)); a1[1] += bf2f((u16)(q1.x >> 16));
            a1[2] += bf2f((u16)(q1.y & 0xFFFF)); a1[3] += bf2f((u16)(q1.y >> 16));
            a2[0] += bf2f((u16)(q2.x & 0xFFFF)); a2[1] += bf2f((u16)(q2.x >> 16));
            a2[2] += bf2f((u16)(q2.y & 0xFFFF)); a2[3] += bf2f((u16)(q2.y >> 16));
            a3[0] += bf2f((u16)(q3.x & 0xFFFF)); a3[1] += bf2f((u16)(q3.x >> 16));
            a3[2] += bf2f((u16)(q3.y & 0xFFFF)); a3[3] += bf2f((u16)(q3.y >> 16));
            j += 4;
        }
        for (; j < end; ++j) {
            uint2v q0 = *(const uint2v*)&y[(size_t)__builtin_nontemporal_load(col + j) * DCH + c0];
            a0[0] += bf2f((u16)(q0.x & 0xFFFF)); a0[1] += bf2f((u16)(q0.x >> 16));
            a0[2] += bf2f((u16)(q0.y & 0xFFFF)); a0[3] += bf2f((u16)(q0.y >> 16));
        }
        float dn = dinv[n];
        floatx4 o;
        o[0] = fmaf((a0[0] + a1[0]) + (a2[0] + a3[0]), dn, bb[0]);
        o[1] = fmaf((a0[1] + a1[1]) + (a2[1] + a3[1]), dn, bb[1]);
        o[2] = fmaf((a0[2] + a1[2]) + (a2[2] + a3[2]), dn, bb[2]);
        o[3] = fmaf((a0[3] + a1[3]) + (a2[3] + a3[3]), dn, bb[3]);
        __builtin_nontemporal_store(o, (floatx4*)&h[(size_t)n * DCH + c0]);
        ps[0] += o[0]; pq[0] += o[0] * o[0];
        ps[1] += o[1]; pq[1] += o[1] * o[1];
        ps[2] += o[2]; pq[2] += o[2] * o[2];
        ps[3] += o[3]; pq[3] += o[3] * o[3];

        n = n2; beg = begN; end = endN; qs = qsN;
    }
    __shared__ float lps[8][DCH], lpq[8][DCH];   // 8 KB
    #pragma unroll
    for (int k = 0; k < 4; ++k) { lps[hw][c0 + k] = ps[k]; lpq[hw][c0 + k] = pq[k]; }
    __syncthreads();
    if (t < DCH) {
        // rotate channel by block to de-synchronize hot-address atomics
        int ch = (t + blockIdx.x * 16) & 127;
        float s = 0.f, q = 0.f;
        #pragma unroll
        for (int i = 0; i < 8; ++i) { s += lps[i][ch]; q += lpq[i][ch]; }
        atomicAdd(&sums[ch], s);
        atomicAdd(&sumsq[ch], q);
    }
}

// ---------- fallback (R5-proven) atomic-path kernels ----------
__global__ void gemm_valu_kernel(const void* x, const void* W, const float* dinv,
                                 const int* ws_i, void* y, int N) {
    __shared__ float WsF[64 * DCH];
    __shared__ float xs[ROWS * DCH];
    int isbf = ws_i[1];
    int t = threadIdx.x;
    int r0 = blockIdx.x * ROWS;
    for (int i = t; i < ROWS * DCH; i += 256) {
        int r = r0 + (i >> 7);
        xs[i] = (r < N) ? ldf(x, r * DCH + (i & 127), isbf) : 0.f;
    }
    int d = t & 127, rh = t >> 7;
    float s[8];
    #pragma unroll
    for (int j = 0; j < 8; ++j) s[j] = 0.f;
    for (int half = 0; half < 2; ++half) {
        __syncthreads();
        for (int i = t; i < 64 * DCH; i += 256)
            WsF[i] = ldf(W, half * 64 * DCH + i, isbf);
        __syncthreads();
        #pragma unroll
        for (int j = 0; j < 8; ++j) {
            int rr = rh + 2 * j;
            float a = s[j];
            #pragma unroll 16
            for (int k = 0; k < 64; ++k)
                a = fmaf(xs[rr * DCH + half * 64 + k], WsF[k * DCH + d], a);
            s[j] = a;
        }
    }
    #pragma unroll
    for (int j = 0; j < 8; ++j) {
        int r = r0 + rh + 2 * j;
        if (r < N) {
            float v = s[j] * dinv[r];
            if (isbf) ((u16*)y)[r * DCH + d] = f2bf(v);
            else      ((float*)y)[r * DCH + d] = v;
        }
    }
}

__global__ void scatter_kernel(const int* ei, int E, const int* ws_i,
                               const void* y, float* acc, int N) {
    int is64 = ws_i[0], isbf = ws_i[1];
    int gid = blockIdx.x * 256 + threadIdx.x;
    int e = gid >> 5;
    if (e >= E) return;
    int c0 = (gid & 31) * 4;
    int s = is64 ? ei[2 * e] : ei[e];
    int d = is64 ? ei[2 * E + 2 * e] : ei[E + e];
    s = min(max(s, 0), N - 1);
    d = min(max(d, 0), N - 1);
    float v0, v1, v2, v3;
    if (isbf) {
        uint2 raw = *(const uint2*)&((const u16*)y)[s * DCH + c0];
        v0 = bf2f((u16)(raw.x & 0xFFFF)); v1 = bf2f((u16)(raw.x >> 16));
        v2 = bf2f((u16)(raw.y & 0xFFFF)); v3 = bf2f((u16)(raw.y >> 16));
    } else {
        float4 raw = *(const float4*)&((const float*)y)[s * DCH + c0];
        v0 = raw.x; v1 = raw.y; v2 = raw.z; v3 = raw.w;
    }
    float* a = &acc[d * DCH + c0];
    atomicAdd(a + 0, v0);
    atomicAdd(a + 1, v1);
    atomicAdd(a + 2, v2);
    atomicAdd(a + 3, v3);
}

__global__ void bnstat_kernel(const void* y, float* acc, const float* dinv,
                              const void* b, int* ws_i,
                              float* sums, float* sumsq, int total) {
    int isbf = ws_i[1];
    int t = threadIdx.x;
    int d = t & 127;
    float bb = ldf(b, d, isbf);
    float ps = 0.f, pq = 0.f;
    int stride = gridDim.x * 256;
    for (int i = blockIdx.x * 256 + t; i < total; i += stride) {
        int r = i >> 7;
        float yv = isbf ? bf2f(((const u16*)y)[i]) : ((const float*)y)[i];
        float v = (yv + acc[i]) * dinv[r] + bb;
        acc[i] = v;
        ps += v;
        pq += v * v;
    }
    __shared__ float ls[256], lq[256];
    ls[t] = ps; lq[t] = pq;
    __syncthreads();
    if (t < 128) {
        atomicAdd(&sums[d], ls[t] + ls[t + 128]);
        atomicAdd(&sumsq[d], lq[t] + lq[t + 128]);
    }
}
// --------------------------------------------------------------

// out_kernel with diag folded in: all errbits from prior kernels are stable
// before this launches (stream-serialized); the var-check is block-uniform
// (every block sees identical sums/sumsq), so each block can decide paint vs
// normal locally and identically. Saves the trailing diag dispatch.
__global__ void out_kernel(const float* h, const void* x,
                           const void* gamma, const void* beta,
                           int* ws_i, const float* sums, const float* sumsq,
                           void* out, int total, float invN) {
    __shared__ float sc[DCH], sh[DCH];
    __shared__ int s_bad;
    int isbf = ws_i[1];
    int t = threadIdx.x;
    if (t == 0) s_bad = ws_i[2];
    __syncthreads();
    if (t < DCH) {
        float mean = sums[t] * invN;
        float var = fmaxf(sumsq[t] * invN - mean * mean, 0.f);
        float s = ldf(gamma, t, isbf) * rsqrtf(var + BN_EPS);
        if (!(var < 1e8f && fabsf(s) < 1e6f)) atomicOr(&s_bad, 32);
        sc[t] = s;
        sh[t] = ldf(beta, t, isbf) - mean * s;
    }
    __syncthreads();
    int e = s_bad;
    int stride = gridDim.x * 256;
    if (e) {                                   // diagnostic paint (uniform)
        float v = 4096.f + 32.f * (float)(e & 63);
        if (isbf) {
            u16 code = f2bf(v);
            for (int i = blockIdx.x * 256 + t; i < total; i += stride)
                ((u16*)out)[i] = code;
        } else {
            for (int i = blockIdx.x * 256 + t; i < total; i += stride)
                ((float*)out)[i] = v;
        }
        return;
    }
    int total4 = total >> 2;
    int i0 = blockIdx.x * 256 + t;
    // channel base is loop-invariant: stride*4 is a multiple of 128
    int d0 = (i0 << 2) & 127;
    float c0 = sc[d0], c1 = sc[d0 + 1], c2 = sc[d0 + 2], c3 = sc[d0 + 3];
    float f0 = sh[d0], f1 = sh[d0 + 1], f2 = sh[d0 + 2], f3 = sh[d0 + 3];
    if (isbf) {
        for (int i = i0; i < total4; i += stride) {
            floatx4 hv = __builtin_nontemporal_load((const floatx4*)h + i);
            uint2v xv = __builtin_nontemporal_load((const uint2v*)x + i);
            float v0 = fmaxf(fmaf(hv[0], c0, f0), 0.f) + bf2f((u16)(xv.x & 0xFFFF));
            float v1 = fmaxf(fmaf(hv[1], c1, f1), 0.f) + bf2f((u16)(xv.x >> 16));
            float v2 = fmaxf(fmaf(hv[2], c2, f2), 0.f) + bf2f((u16)(xv.y & 0xFFFF));
            float v3 = fmaxf(fmaf(hv[3], c3, f3), 0.f) + bf2f((u16)(xv.y >> 16));
            uint2v o;
            o.x = (unsigned)f2bf(v0) | ((unsigned)f2bf(v1) << 16);
            o.y = (unsigned)f2bf(v2) | ((unsigned)f2bf(v3) << 16);
            __builtin_nontemporal_store(o, (uint2v*)out + i);
        }
    } else {
        for (int i = i0; i < total4; i += stride) {
            floatx4 hv = __builtin_nontemporal_load((const floatx4*)h + i);
            floatx4 xv = __builtin_nontemporal_load((const floatx4*)x + i);
            floatx4 o;
            o[0] = fmaxf(fmaf(hv[0], c0, f0), 0.f) + xv[0];
            o[1] = fmaxf(fmaf(hv[1], c1, f1), 0.f) + xv[1];
            o[2] = fmaxf(fmaf(hv[2], c2, f2), 0.f) + xv[2];
            o[3] = fmaxf(fmaf(hv[3], c3, f3), 0.f) + xv[3];
            __builtin_nontemporal_store(o, (floatx4*)out + i);
        }
    }
    // scalar tail (total % 4 != 0 never happens for D=128, kept for safety)
    for (int i = (total4 << 2) + i0; i < total; i += stride) {
        int d = i & 127;
        float v = fmaxf(fmaf(h[i], sc[d], sh[d]), 0.f);
        if (isbf) ((u16*)out)[i] = f2bf(v + bf2f(((const u16*)x)[i]));
        else      ((float*)out)[i] = v + ((const float*)x)[i];
    }
}

extern "C" void kernel_launch(void* const* d_in, const int* in_sizes, int n_in,
                              void* d_out, int out_size, void* d_ws, size_t ws_size,
                              hipStream_t stream) {
    const void* x     = d_in[0];
    const void* W     = d_in[1];
    const void* b     = d_in[2];
    const void* gamma = d_in[3];
    const void* beta  = d_in[4];
    const int*  ei    = (const int*)d_in[5];

    const int N  = in_sizes[0] / DCH;   // 50000
    const int E  = in_sizes[5] / 2;     // 640000
    const int ND = N * DCH;             // 6,400,000
    const int P  = (N + 1023) / 1024;   // scan partials (49)

    char* wsb = (char*)d_ws;
    int*  ws_i = (int*)wsb;

    // layout: ws_i 64B | Wb 32KB | deg[N] | sums[128] | sumsq[128] | rowptr[N+1] | dinv[N] | part[256] | h[ND] | col[E]
    size_t o_wb   = 64;
    size_t o_deg  = o_wb + 32768;
    size_t o_sum  = o_deg + 4 * (size_t)N;
    size_t o_sq   = o_sum + 512;
    size_t o_rp   = o_sq + 512;
    size_t o_dinv = o_rp + 4 * ((size_t)N + 1) + 4;
    size_t o_part = o_dinv + 4 * (size_t)N;
    size_t o_h    = (o_part + 1024 + 255) & ~(size_t)255;
    size_t o_col  = o_h + 4 * (size_t)ND;
    size_t need_csr = o_col + 4 * (size_t)E;

    (void)hipGetLastError();

    if (ws_size >= need_csr && P <= 256) {
        u16*   Wb    = (u16*)(wsb + o_wb);
        int*   deg   = (int*)(wsb + o_deg);
        float* sums  = (float*)(wsb + o_sum);
        float* sumsq = (float*)(wsb + o_sq);
        int*   rowptr= (int*)(wsb + o_rp);
        float* dinv  = (float*)(wsb + o_dinv);
        int*   part  = (int*)(wsb + o_part);
        float* h     = (float*)(wsb + o_h);
        int*   col   = (int*)(wsb + o_col);
        u16*   y     = (u16*)d_out;   // bf16 y in d_out until out_kernel overwrites

        int GB = (N + 63) / 64;            // gemm blocks
        int FB = (E + 255) / 256;          // fillcsr blocks (covers both edge formats)

        // zero ws_i + Wb + deg + sums + sumsq with a KERNEL (R5 lesson: host
        // memset on the capture path was the abort).
        zero_kernel<<<128, 256, 0, stream>>>((float*)wsb, (int)((o_sq + 512) / 4));
        prep_deg_kernel<<<1250, 256, 0, stream>>>(ei, E, (const u16*)x, ws_i,
                                                  W, Wb, deg, N);
        scanA_kernel<<<P, 256, 0, stream>>>(deg, part, N);
        scanC_kernel<<<P, 256, 0, stream>>>(deg, part, rowptr, dinv, N, P);
        fill_gemm_kernel<<<GB + FB, 256, 0, stream>>>(ei, E, ws_i, deg, col,
                                                      x, Wb, dinv, y, N, GB);
        gather_stats_kernel<<<512, 256, 0, stream>>>(rowptr, col, y, dinv, b, ws_i,
                                                     h, sums, sumsq, N);
        out_kernel<<<2048, 256, 0, stream>>>(h, x, gamma, beta, ws_i, sums, sumsq,
                                             d_out, ND, 1.0f / (float)N);
    } else {
        // R5-proven fallback: ws_i | deg | dinv | sums | sumsq | acc
        int*   deg   = (int*)(wsb + 16);
        float* dinv  = (float*)(wsb + 16 + 4 * (size_t)N);
        float* sums  = (float*)(wsb + 16 + 8 * (size_t)N);
        float* sumsq = sums + DCH;
        float* acc   = sumsq + DCH;
        size_t need = 16 + 8 * (size_t)N + 1024 + 4 * (size_t)ND;
        if (ws_size < need) {
            int mb = (int)(ws_size >> 20); if (mb > 127) mb = 127;
            float v = 2048.f + 16.f * (float)mb;
            unsigned u; __builtin_memcpy(&u, &v, 4);
            paint_kernel<<<1024, 256, 0, stream>>>((u16*)d_out, out_size, u >> 16);
            return;
        }
        detect_kernel<<<1, 256, 0, stream>>>(ei, 2 * E, (const u16*)x, ws_i);
        zero_kernel<<<2048, 256, 0, stream>>>((float*)(wsb + 16), 2 * N + 256 + ND);
        deg_kernel<<<(E + 255) / 256, 256, 0, stream>>>(ei, E, ws_i, deg, N);
        dinv_kernel<<<(N + 255) / 256, 256, 0, stream>>>(deg, dinv, N, ws_i);
        gemm_valu_kernel<<<(N + ROWS - 1) / ROWS, 256, 0, stream>>>(x, W, dinv, ws_i, d_out, N);
        scatter_kernel<<<(E * 32 + 255) / 256, 256, 0, stream>>>(ei, E, ws_i, d_out, acc, N);
        bnstat_kernel<<<240, 256, 0, stream>>>(d_out, acc, dinv, b, ws_i, sums, sumsq, ND);
        out_kernel<<<256, 256, 0, stream>>>(acc, x, gamma, beta, ws_i, sums, sumsq,
                                            d_out, ND, 1.0f / (float)N);
    }

    if (hipGetLastError() != hipSuccess)
        hipMemsetAsync(d_out, 0x42, (size_t)out_size * 2, stream);
}

// Round 11
// 234.899 us; speedup vs baseline: 1.0183x; 1.0183x over previous
//
#include <hip/hip_runtime.h>

#define DCH 128
#define ROWS 16
#define BN_EPS 1e-5f

typedef unsigned short u16;
typedef __attribute__((ext_vector_type(8))) short short8;
typedef __attribute__((ext_vector_type(4))) float floatx4;
typedef __attribute__((ext_vector_type(2))) unsigned uint2v;

__device__ __forceinline__ float bf2f(u16 u) {
    return __uint_as_float(((unsigned)u) << 16);
}
__device__ __forceinline__ u16 f2bf(float f) {
    unsigned u = __float_as_uint(f);
    u += 0x7FFFu + ((u >> 16) & 1u);   // RNE, finite inputs
    return (u16)(u >> 16);
}
__device__ __forceinline__ float ldf(const void* p, int i, int isbf) {
    return isbf ? bf2f(((const u16*)p)[i]) : ((const float*)p)[i];
}

__global__ void zero_kernel(float* p, int n) {
    int stride = gridDim.x * 256;
    for (int i = blockIdx.x * 256 + threadIdx.x; i < n; i += stride) p[i] = 0.f;
}

__global__ void paint_kernel(u16* out, int n, unsigned val) {
    int stride = gridDim.x * 256;
    for (int i = blockIdx.x * 256 + threadIdx.x; i < n; i += stride) out[i] = (u16)val;
}

// ws_i[0]=edge-is-int64  ws_i[1]=floats-are-bf16  ws_i[2]=errbits
// Workspace head pre-zeroed by zero_kernel (R5 lesson: NOT host memset — it
// failed under graph capture, leaving deg garbage -> OOB col writes).
// Every block recomputes is64/isbf locally from the same leading bytes
// (deterministic), packs a slice of W, and counts a degree slice.
// int64 fast path reads only the DEST half of ei (src bounds-check was
// diagnostic-only; fillcsr clamps src anyway) — halves prep's edge traffic.
__global__ void prep_deg_kernel(const int* ei, int E, const u16* xw, int* ws_i,
                                const void* W, u16* Wb, int* deg, int N) {
    int t = threadIdx.x;
    __shared__ int s_nz, s_hits;
    if (t == 0) { s_nz = 0; s_hits = 0; }
    __syncthreads();
    int ewords = 2 * E;
    int nz = 0;
    for (int i = t; i < 1024; i += 256) {
        int w = 2 * i + 1;
        if (w < ewords) nz |= ei[w];
    }
    if (nz) atomicOr(&s_nz, 1);
    unsigned m = (xw[2 * t] >> 8) & 0x7F;
    if (m >= 0x3B && m <= 0x43) atomicAdd(&s_hits, 1);
    __syncthreads();
    int is64 = (s_nz == 0) ? 1 : 0;
    int isbf = (s_hits >= 128) ? 1 : 0;
    if (blockIdx.x == 0 && t == 0) {
        ws_i[0] = is64;
        ws_i[1] = isbf;
        // ws_i[2] (errbits) pre-zeroed; other blocks may atomicOr it now.
    }
    int gid = blockIdx.x * 256 + t;
    int gthreads = gridDim.x * 256;
    // pack W: Wb[((nt*4+kk)*64+lane)*8+j] = bf16(W[(kk*32+(lane>>4)*8+j)*128 + nt*16+(lane&15)])
    for (int idx = gid; idx < DCH * DCH; idx += gthreads) {
        int j = idx & 7, lane = (idx >> 3) & 63, kk = (idx >> 9) & 3, nt = idx >> 11;
        int k = kk * 32 + (lane >> 4) * 8 + j;
        int n = nt * 16 + (lane & 15);
        Wb[idx] = f2bf(ldf(W, k * DCH + n, isbf));
    }
    // degree count
    if (is64 && !(E & 1)) {
        int P2 = E >> 1;
        for (int p = gid; p < P2; p += gthreads) {
            int4 dp = ((const int4*)(ei + 2 * E))[p];
            if (((unsigned)dp.x >= (unsigned)N) || ((unsigned)dp.z >= (unsigned)N))
                atomicOr(&ws_i[2], 2);
            atomicAdd(&deg[min(max(dp.x, 0), N - 1)], 1);
            atomicAdd(&deg[min(max(dp.z, 0), N - 1)], 1);
        }
    } else {
        for (int e = gid; e < E; e += gthreads) {
            int s = is64 ? ei[2 * e] : ei[e];
            int d = is64 ? ei[2 * E + 2 * e] : ei[E + e];
            if (((unsigned)s >= (unsigned)N) || ((unsigned)d >= (unsigned)N))
                atomicOr(&ws_i[2], 2);
            atomicAdd(&deg[min(max(d, 0), N - 1)], 1);
        }
    }
}

__global__ void detect_kernel(const int* ei, int ewords, const u16* xw, int* ws_i) {
    __shared__ int s_nz, s_hits;
    int t = threadIdx.x;
    if (t == 0) { s_nz = 0; s_hits = 0; }
    __syncthreads();
    int nz = 0;
    for (int i = t; i < 1024; i += 256) {
        int w = 2 * i + 1;
        if (w < ewords) nz |= ei[w];
    }
    if (nz) atomicOr(&s_nz, 1);
    unsigned m = (xw[2 * t] >> 8) & 0x7F;
    if (m >= 0x3B && m <= 0x43) atomicAdd(&s_hits, 1);
    __syncthreads();
    if (t == 0) {
        ws_i[0] = (s_nz == 0) ? 1 : 0;
        ws_i[1] = (s_hits >= 128) ? 1 : 0;
        ws_i[2] = 0;
    }
}

__global__ void deg_kernel(const int* ei, int E, int* ws_i, int* deg, int N) {
    int is64 = ws_i[0];
    int i = blockIdx.x * 256 + threadIdx.x;
    if (i < E) {
        int s = is64 ? ei[2 * i] : ei[i];
        int d = is64 ? ei[2 * E + 2 * i] : ei[E + i];
        if (((unsigned)s >= (unsigned)N) || ((unsigned)d >= (unsigned)N))
            atomicOr(&ws_i[2], 2);
        d = min(max(d, 0), N - 1);
        atomicAdd(&deg[d], 1);
    }
}

__global__ void dinv_kernel(const int* deg, float* dinv, int N, int* ws_i) {
    int i = blockIdx.x * 256 + threadIdx.x;
    if (i < N) {
        float v = rsqrtf((float)(deg[i] + 1));
        if (!(v > 0.f && v <= 1.001f)) atomicOr(&ws_i[2], 4);
        dinv[i] = v;
    }
}

// ---- scan of deg -> rowptr (R6-proven coalesced pair; R7 lesson: the
// single-block scan1 had per-thread-contiguous = per-wave-strided reads ->
// 64 cache lines per load, 147us on one CU. Coalesced grid-parallel wins.)
__global__ void scanA_kernel(const int* deg, int* part, int N) {
    int base = blockIdx.x * 1024 + threadIdx.x * 4;
    int s = 0;
    #pragma unroll
    for (int j = 0; j < 4; ++j) {
        int i = base + j;
        if (i < N) s += deg[i];
    }
    #pragma unroll
    for (int o = 1; o < 64; o <<= 1) s += __shfl_xor(s, o, 64);
    __shared__ int ws4[4];
    if ((threadIdx.x & 63) == 0) ws4[threadIdx.x >> 6] = s;
    __syncthreads();
    if (threadIdx.x == 0) part[blockIdx.x] = ws4[0] + ws4[1] + ws4[2] + ws4[3];
}

__global__ void scanC_kernel(int* deg_cursor, const int* part, int* rowptr,
                             float* dinv, int N, int P) {
    __shared__ int wsum[4], wsP[4];
    int t = threadIdx.x, lane = t & 63, w = t >> 6;
    // local exclusive base: sum part[j] for j < blockIdx.x  (raw block sums, P<=256)
    int pv = (t < P && t < (int)blockIdx.x) ? part[t] : 0;
    #pragma unroll
    for (int o = 1; o < 64; o <<= 1) pv += __shfl_xor(pv, o, 64);
    if (lane == 0) wsP[w] = pv;

    int base = blockIdx.x * 1024 + t * 4;
    int v[4], ts = 0;
    #pragma unroll
    for (int j = 0; j < 4; ++j) {
        int i = base + j;
        v[j] = (i < N) ? deg_cursor[i] : 0;
        ts += v[j];
    }
    int sc = ts;
    #pragma unroll
    for (int o = 1; o < 64; o <<= 1) {
        int u = __shfl_up(sc, o, 64);
        if (lane >= o) sc += u;
    }
    if (lane == 63) wsum[w] = sc;
    __syncthreads();
    if (t < 4) {
        int s = wsum[t];
        #pragma unroll
        for (int o = 1; o < 4; o <<= 1) {
            int u = __shfl_up(s, o, 4);
            if (t >= o) s += u;
        }
        wsum[t] = s;
    }
    __syncthreads();
    int blockbase = wsP[0] + wsP[1] + wsP[2] + wsP[3];
    int run = sc - ts + (w ? wsum[w - 1] : 0) + blockbase;
    #pragma unroll
    for (int j = 0; j < 4; ++j) {
        int i = base + j;
        if (i < N) {
            deg_cursor[i] = run;                       // exclusive (cursor start)
            run += v[j];
            rowptr[i + 1] = run;                       // inclusive
            dinv[i] = rsqrtf((float)(v[j] + 1));       // fused dinv
        }
    }
    if (blockIdx.x == 0 && t == 0) rowptr[0] = 0;
}
// ------------------------------------------------------------------

// Fused: blocks [0,GB) run the MFMA GEMM (proven body), blocks [GB,..) run
// fillcsr (proven body). Both depend only on the scan (cursor/dinv) and are
// resource-disjoint (MFMA+stores vs atomics) -> one dispatch, real overlap.
__global__ void fill_gemm_kernel(const int* ei, int E, const int* ws_i,
                                 int* cursor, int* col,
                                 const void* x, const u16* Wb, const float* dinv,
                                 u16* y, int N, int GB) {
    int t = threadIdx.x;
    if ((int)blockIdx.x < GB) {
        // ---- GEMM body (verbatim) ----
        int isbf = ws_i[1];
        int wv = t >> 6, lane = t & 63;
        int quad = lane >> 4, l16 = lane & 15;
        int r0 = blockIdx.x * 64 + wv * 16;
        int rl = min(r0 + l16, N - 1);
        short8 a[4];
        if (isbf) {
            const u16* xp = (const u16*)x + (size_t)rl * DCH + quad * 8;
            #pragma unroll
            for (int kk = 0; kk < 4; ++kk)
                a[kk] = *(const short8*)(xp + kk * 32);
        } else {
            const float* xp = (const float*)x + (size_t)rl * DCH + quad * 8;
            #pragma unroll
            for (int kk = 0; kk < 4; ++kk) {
                float4 f0 = *(const float4*)(xp + kk * 32);
                float4 f1 = *(const float4*)(xp + kk * 32 + 4);
                short8 aa;
                aa[0] = (short)f2bf(f0.x); aa[1] = (short)f2bf(f0.y);
                aa[2] = (short)f2bf(f0.z); aa[3] = (short)f2bf(f0.w);
                aa[4] = (short)f2bf(f1.x); aa[5] = (short)f2bf(f1.y);
                aa[6] = (short)f2bf(f1.z); aa[7] = (short)f2bf(f1.w);
                a[kk] = aa;
            }
        }
        floatx4 acc[8];
        #pragma unroll
        for (int i = 0; i < 8; ++i) acc[i] = (floatx4)(0.f);
        #pragma unroll
        for (int nt = 0; nt < 8; ++nt) {
            #pragma unroll
            for (int kk = 0; kk < 4; ++kk) {
                short8 bfr = *(const short8*)&Wb[(((nt << 2) | kk) * 64 + lane) * 8];
                acc[nt] = __builtin_amdgcn_mfma_f32_16x16x32_bf16(a[kk], bfr, acc[nt], 0, 0, 0);
            }
        }
        #pragma unroll
        for (int i = 0; i < 4; ++i) {
            int row = r0 + quad * 4 + i;
            if (row < N) {
                float dv = dinv[row];
                #pragma unroll
                for (int nt = 0; nt < 8; ++nt)
                    y[(size_t)row * DCH + nt * 16 + l16] = f2bf(acc[nt][i] * dv);
            }
        }
    } else {
        // ---- fillcsr body (verbatim, block index shifted) ----
        int is64 = ws_i[0];
        int i = (blockIdx.x - GB) * 256 + t;
        if (is64 && !(E & 1)) {
            if (2 * i < E) {
                int4 sp = ((const int4*)ei)[i];
                int4 dp = ((const int4*)(ei + 2 * E))[i];
                int s0 = min(max(sp.x, 0), N - 1), d0 = min(max(dp.x, 0), N - 1);
                int s1 = min(max(sp.z, 0), N - 1), d1 = min(max(dp.z, 0), N - 1);
                int p0 = atomicAdd(&cursor[d0], 1);
                if ((unsigned)p0 < (unsigned)E) col[p0] = s0;   // defensive bound
                int p1 = atomicAdd(&cursor[d1], 1);
                if ((unsigned)p1 < (unsigned)E) col[p1] = s1;
            }
        } else if (i < E) {
            int s = is64 ? ei[2 * i] : ei[i];
            int d = is64 ? ei[2 * E + 2 * i] : ei[E + i];
            s = min(max(s, 0), N - 1);
            d = min(max(d, 0), N - 1);
            int pos = atomicAdd(&cursor[d], 1);
            if ((unsigned)pos < (unsigned)E) col[pos] = s;
        }
    }
}

// gather + BN-stats fused. Half-wave per node, lane owns 4 channels (uint2v 8B
// loads). 1024 blocks = 8192 streams: MEASURED MINIMUM of the stream-count
// curve — 16384 streams: 77.9us/94MB (thrash); 8192: 59.5us/68.4MB; 4096:
// 63.3us/67.4MB (R10: traffic floor ~67MB is flat below 8192, concurrency
// loss dominates). Per-stream MLP probed (4-deep == 8-deep, R2). Deep
// per-stream pipeline: 8 y-gathers in flight, col prefetched a group ahead,
// next node's rowptr+self-row prefetched. h store + col loads nontemporal.
__global__ __launch_bounds__(256, 4)
void gather_stats_kernel(const int* rowptr, const int* col, const u16* y,
                         const float* dinv, const void* b, const int* ws_i,
                         float* h, float* sums, float* sumsq, int N) {
    int isbf = ws_i[1];
    int t = threadIdx.x;
    int hw = t >> 5;                 // half-wave id in block [0,8)
    int l32 = t & 31;
    int c0 = l32 * 4;
    float bb[4];
    #pragma unroll
    for (int k = 0; k < 4; ++k) bb[k] = ldf(b, c0 + k, isbf);
    float ps[4] = {0.f, 0.f, 0.f, 0.f}, pq[4] = {0.f, 0.f, 0.f, 0.f};
    int stream_id = blockIdx.x * 8 + hw;
    int nstreams = gridDim.x * 8;

    int n = stream_id;
    int beg = 0, end = 0;
    uint2v qs = (uint2v)(0u);
    if (n < N) {
        beg = rowptr[n];
        end = rowptr[n + 1];
        qs = *(const uint2v*)&y[(size_t)n * DCH + c0];
    }
    while (n < N) {
        // prefetch next node's rowptr + self-row while this node's edges stream
        int n2 = n + nstreams;
        int begN = 0, endN = 0;
        uint2v qsN = (uint2v)(0u);
        if (n2 < N) {
            begN = rowptr[n2];
            endN = rowptr[n2 + 1];
            qsN = *(const uint2v*)&y[(size_t)n2 * DCH + c0];
        }

        float a0[4] = { bf2f((u16)(qs.x & 0xFFFF)), bf2f((u16)(qs.x >> 16)),
                        bf2f((u16)(qs.y & 0xFFFF)), bf2f((u16)(qs.y >> 16)) };
        float a1[4] = {0.f, 0.f, 0.f, 0.f};
        float a2[4] = {0.f, 0.f, 0.f, 0.f};
        float a3[4] = {0.f, 0.f, 0.f, 0.f};
        int j = beg;
        int s0 = 0, s1 = 0, s2 = 0, s3 = 0, s4 = 0, s5 = 0, s6 = 0, s7 = 0;
        bool have8 = (j + 7 < end);
        if (have8) {
            s0 = __builtin_nontemporal_load(col + j);
            s1 = __builtin_nontemporal_load(col + j + 1);
            s2 = __builtin_nontemporal_load(col + j + 2);
            s3 = __builtin_nontemporal_load(col + j + 3);
            s4 = __builtin_nontemporal_load(col + j + 4);
            s5 = __builtin_nontemporal_load(col + j + 5);
            s6 = __builtin_nontemporal_load(col + j + 6);
            s7 = __builtin_nontemporal_load(col + j + 7);
        }
        while (have8) {
            // 8 independent y-row gathers in flight
            uint2v q0 = *(const uint2v*)&y[(size_t)s0 * DCH + c0];
            uint2v q1 = *(const uint2v*)&y[(size_t)s1 * DCH + c0];
            uint2v q2 = *(const uint2v*)&y[(size_t)s2 * DCH + c0];
            uint2v q3 = *(const uint2v*)&y[(size_t)s3 * DCH + c0];
            uint2v q4 = *(const uint2v*)&y[(size_t)s4 * DCH + c0];
            uint2v q5 = *(const uint2v*)&y[(size_t)s5 * DCH + c0];
            uint2v q6 = *(const uint2v*)&y[(size_t)s6 * DCH + c0];
            uint2v q7 = *(const uint2v*)&y[(size_t)s7 * DCH + c0];
            // prefetch next group's col indices before stalling on q0..q7
            int jn = j + 8;
            bool haven = (jn + 7 < end);
            if (haven) {
                s0 = __builtin_nontemporal_load(col + jn);
                s1 = __builtin_nontemporal_load(col + jn + 1);
                s2 = __builtin_nontemporal_load(col + jn + 2);
                s3 = __builtin_nontemporal_load(col + jn + 3);
                s4 = __builtin_nontemporal_load(col + jn + 4);
                s5 = __builtin_nontemporal_load(col + jn + 5);
                s6 = __builtin_nontemporal_load(col + jn + 6);
                s7 = __builtin_nontemporal_load(col + jn + 7);
            }
            a0[0] += bf2f((u16)(q0.x & 0xFFFF)); a0[1] += bf2f((u16)(q0.x >> 16));
            a0[2] += bf2f((u16)(q0.y & 0xFFFF)); a0[3] += bf2f((u16)(q0.y >> 16));
            a1[0] += bf2f((u16)(q1.x & 0xFFFF)); a1[1] += bf2f((u16)(q1.x >> 16));
            a1[2] += bf2f((u16)(q1.y & 0xFFFF)); a1[3] += bf2f((u16)(q1.y >> 16));
            a2[0] += bf2f((u16)(q2.x & 0xFFFF)); a2[1] += bf2f((u16)(q2.x >> 16));
            a2[2] += bf2f((u16)(q2.y & 0xFFFF)); a2[3] += bf2f((u16)(q2.y >> 16));
            a3[0] += bf2f((u16)(q3.x & 0xFFFF)); a3[1] += bf2f((u16)(q3.x >> 16));
            a3[2] += bf2f((u16)(q3.y & 0xFFFF)); a3[3] += bf2f((u16)(q3.y >> 16));
            a0[0] += bf2f((u16)(q4.x & 0xFFFF)); a0[1] += bf2f((u16)(q4.x >> 16));
            a0[2] += bf2f((u16)(q4.y & 0xFFFF)); a0[3] += bf2f((u16)(q4.y >> 16));
            a1[0] += bf2f((u16)(q5.x & 0xFFFF)); a1[1] += bf2f((u16)(q5.x >> 16));
            a1[2] += bf2f((u16)(q5.y & 0xFFFF)); a1[3] += bf2f((u16)(q5.y >> 16));
            a2[0] += bf2f((u16)(q6.x & 0xFFFF)); a2[1] += bf2f((u16)(q6.x >> 16));
            a2[2] += bf2f((u16)(q6.y & 0xFFFF)); a2[3] += bf2f((u16)(q6.y >> 16));
            a3[0] += bf2f((u16)(q7.x & 0xFFFF)); a3[1] += bf2f((u16)(q7.x >> 16));
            a3[2] += bf2f((u16)(q7.y & 0xFFFF)); a3[3] += bf2f((u16)(q7.y >> 16));
            j = jn; have8 = haven;
        }
        if (j + 3 < end) {            // at most one 4-group after the 8-loop
            s0 = __builtin_nontemporal_load(col + j);
            s1 = __builtin_nontemporal_load(col + j + 1);
            s2 = __builtin_nontemporal_load(col + j + 2);
            s3 = __builtin_nontemporal_load(col + j + 3);
            uint2v q0 = *(const uint2v*)&y[(size_t)s0 * DCH + c0];
            uint2v q1 = *(const uint2v*)&y[(size_t)s1 * DCH + c0];
            uint2v q2 = *(const uint2v*)&y[(size_t)s2 * DCH + c0];
            uint2v q3 = *(const uint2v*)&y[(size_t)s3 * DCH + c0];
            a0[0] += bf2f((u16)(q0.x & 0xFFFF)); a0[1] += bf2f((u16)(q0.x >> 16));
            a0[2] += bf2f((u16)(q0.y & 0xFFFF)); a0[3] += bf2f((u16)(q0.y >> 16));
            a1[0] += bf2f((u16)(q1.x & 0xFFFF)); a1[1] += bf2f((u16)(q1.x >> 16));
            a1[2] += bf2f((u16)(q1.y & 0xFFFF)); a1[3] += bf2f((u16)(q1.y >> 16));
            a2[0] += bf2f((u16)(q2.x & 0xFFFF)); a2[1] += bf2f((u16)(q2.x >> 16));
            a2[2] += bf2f((u16)(q2.y & 0xFFFF)); a2[3] += bf2f((u16)(q2.y >> 16));
            a3[0] += bf2f((u16)(q3.x & 0xFFFF)); a3[1] += bf2f((u16)(q3.x >> 16));
            a3[2] += bf2f((u16)(q3.y & 0xFFFF)); a3[3] += bf2f((u16)(q3.y >> 16));
            j += 4;
        }
        for (; j < end; ++j) {
            uint2v q0 = *(const uint2v*)&y[(size_t)__builtin_nontemporal_load(col + j) * DCH + c0];
            a0[0] += bf2f((u16)(q0.x & 0xFFFF)); a0[1] += bf2f((u16)(q0.x >> 16));
            a0[2] += bf2f((u16)(q0.y & 0xFFFF)); a0[3] += bf2f((u16)(q0.y >> 16));
        }
        float dn = dinv[n];
        floatx4 o;
        o[0] = fmaf((a0[0] + a1[0]) + (a2[0] + a3[0]), dn, bb[0]);
        o[1] = fmaf((a0[1] + a1[1]) + (a2[1] + a3[1]), dn, bb[1]);
        o[2] = fmaf((a0[2] + a1[2]) + (a2[2] + a3[2]), dn, bb[2]);
        o[3] = fmaf((a0[3] + a1[3]) + (a2[3] + a3[3]), dn, bb[3]);
        __builtin_nontemporal_store(o, (floatx4*)&h[(size_t)n * DCH + c0]);
        ps[0] += o[0]; pq[0] += o[0] * o[0];
        ps[1] += o[1]; pq[1] += o[1] * o[1];
        ps[2] += o[2]; pq[2] += o[2] * o[2];
        ps[3] += o[3]; pq[3] += o[3] * o[3];

        n = n2; beg = begN; end = endN; qs = qsN;
    }
    __shared__ float lps[8][DCH], lpq[8][DCH];   // 8 KB
    #pragma unroll
    for (int k = 0; k < 4; ++k) { lps[hw][c0 + k] = ps[k]; lpq[hw][c0 + k] = pq[k]; }
    __syncthreads();
    if (t < DCH) {
        // rotate channel by block to de-synchronize hot-address atomics
        int ch = (t + blockIdx.x * 16) & 127;
        float s = 0.f, q = 0.f;
        #pragma unroll
        for (int i = 0; i < 8; ++i) { s += lps[i][ch]; q += lpq[i][ch]; }
        atomicAdd(&sums[ch], s);
        atomicAdd(&sumsq[ch], q);
    }
}

// ---------- fallback (R5-proven) atomic-path kernels ----------
__global__ void gemm_valu_kernel(const void* x, const void* W, const float* dinv,
                                 const int* ws_i, void* y, int N) {
    __shared__ float WsF[64 * DCH];
    __shared__ float xs[ROWS * DCH];
    int isbf = ws_i[1];
    int t = threadIdx.x;
    int r0 = blockIdx.x * ROWS;
    for (int i = t; i < ROWS * DCH; i += 256) {
        int r = r0 + (i >> 7);
        xs[i] = (r < N) ? ldf(x, r * DCH + (i & 127), isbf) : 0.f;
    }
    int d = t & 127, rh = t >> 7;
    float s[8];
    #pragma unroll
    for (int j = 0; j < 8; ++j) s[j] = 0.f;
    for (int half = 0; half < 2; ++half) {
        __syncthreads();
        for (int i = t; i < 64 * DCH; i += 256)
            WsF[i] = ldf(W, half * 64 * DCH + i, isbf);
        __syncthreads();
        #pragma unroll
        for (int j = 0; j < 8; ++j) {
            int rr = rh + 2 * j;
            float a = s[j];
            #pragma unroll 16
            for (int k = 0; k < 64; ++k)
                a = fmaf(xs[rr * DCH + half * 64 + k], WsF[k * DCH + d], a);
            s[j] = a;
        }
    }
    #pragma unroll
    for (int j = 0; j < 8; ++j) {
        int r = r0 + rh + 2 * j;
        if (r < N) {
            float v = s[j] * dinv[r];
            if (isbf) ((u16*)y)[r * DCH + d] = f2bf(v);
            else      ((float*)y)[r * DCH + d] = v;
        }
    }
}

__global__ void scatter_kernel(const int* ei, int E, const int* ws_i,
                               const void* y, float* acc, int N) {
    int is64 = ws_i[0], isbf = ws_i[1];
    int gid = blockIdx.x * 256 + threadIdx.x;
    int e = gid >> 5;
    if (e >= E) return;
    int c0 = (gid & 31) * 4;
    int s = is64 ? ei[2 * e] : ei[e];
    int d = is64 ? ei[2 * E + 2 * e] : ei[E + e];
    s = min(max(s, 0), N - 1);
    d = min(max(d, 0), N - 1);
    float v0, v1, v2, v3;
    if (isbf) {
        uint2 raw = *(const uint2*)&((const u16*)y)[s * DCH + c0];
        v0 = bf2f((u16)(raw.x & 0xFFFF)); v1 = bf2f((u16)(raw.x >> 16));
        v2 = bf2f((u16)(raw.y & 0xFFFF)); v3 = bf2f((u16)(raw.y >> 16));
    } else {
        float4 raw = *(const float4*)&((const float*)y)[s * DCH + c0];
        v0 = raw.x; v1 = raw.y; v2 = raw.z; v3 = raw.w;
    }
    float* a = &acc[d * DCH + c0];
    atomicAdd(a + 0, v0);
    atomicAdd(a + 1, v1);
    atomicAdd(a + 2, v2);
    atomicAdd(a + 3, v3);
}

__global__ void bnstat_kernel(const void* y, float* acc, const float* dinv,
                              const void* b, int* ws_i,
                              float* sums, float* sumsq, int total) {
    int isbf = ws_i[1];
    int t = threadIdx.x;
    int d = t & 127;
    float bb = ldf(b, d, isbf);
    float ps = 0.f, pq = 0.f;
    int stride = gridDim.x * 256;
    for (int i = blockIdx.x * 256 + t; i < total; i += stride) {
        int r = i >> 7;
        float yv = isbf ? bf2f(((const u16*)y)[i]) : ((const float*)y)[i];
        float v = (yv + acc[i]) * dinv[r] + bb;
        acc[i] = v;
        ps += v;
        pq += v * v;
    }
    __shared__ float ls[256], lq[256];
    ls[t] = ps; lq[t] = pq;
    __syncthreads();
    if (t < 128) {
        atomicAdd(&sums[d], ls[t] + ls[t + 128]);
        atomicAdd(&sumsq[d], lq[t] + lq[t + 128]);
    }
}
// --------------------------------------------------------------

// out_kernel with diag folded in: all errbits from prior kernels are stable
// before this launches (stream-serialized); the var-check is block-uniform
// (every block sees identical sums/sumsq), so each block can decide paint vs
// normal locally and identically. Saves the trailing diag dispatch.
__global__ void out_kernel(const float* h, const void* x,
                           const void* gamma, const void* beta,
                           int* ws_i, const float* sums, const float* sumsq,
                           void* out, int total, float invN) {
    __shared__ float sc[DCH], sh[DCH];
    __shared__ int s_bad;
    int isbf = ws_i[1];
    int t = threadIdx.x;
    if (t == 0) s_bad = ws_i[2];
    __syncthreads();
    if (t < DCH) {
        float mean = sums[t] * invN;
        float var = fmaxf(sumsq[t] * invN - mean * mean, 0.f);
        float s = ldf(gamma, t, isbf) * rsqrtf(var + BN_EPS);
        if (!(var < 1e8f && fabsf(s) < 1e6f)) atomicOr(&s_bad, 32);
        sc[t] = s;
        sh[t] = ldf(beta, t, isbf) - mean * s;
    }
    __syncthreads();
    int e = s_bad;
    int stride = gridDim.x * 256;
    if (e) {                                   // diagnostic paint (uniform)
        float v = 4096.f + 32.f * (float)(e & 63);
        if (isbf) {
            u16 code = f2bf(v);
            for (int i = blockIdx.x * 256 + t; i < total; i += stride)
                ((u16*)out)[i] = code;
        } else {
            for (int i = blockIdx.x * 256 + t; i < total; i += stride)
                ((float*)out)[i] = v;
        }
        return;
    }
    int total4 = total >> 2;
    int i0 = blockIdx.x * 256 + t;
    // channel base is loop-invariant: stride*4 is a multiple of 128
    int d0 = (i0 << 2) & 127;
    float c0 = sc[d0], c1 = sc[d0 + 1], c2 = sc[d0 + 2], c3 = sc[d0 + 3];
    float f0 = sh[d0], f1 = sh[d0 + 1], f2 = sh[d0 + 2], f3 = sh[d0 + 3];
    if (isbf) {
        for (int i = i0; i < total4; i += stride) {
            floatx4 hv = __builtin_nontemporal_load((const floatx4*)h + i);
            uint2v xv = __builtin_nontemporal_load((const uint2v*)x + i);
            float v0 = fmaxf(fmaf(hv[0], c0, f0), 0.f) + bf2f((u16)(xv.x & 0xFFFF));
            float v1 = fmaxf(fmaf(hv[1], c1, f1), 0.f) + bf2f((u16)(xv.x >> 16));
            float v2 = fmaxf(fmaf(hv[2], c2, f2), 0.f) + bf2f((u16)(xv.y & 0xFFFF));
            float v3 = fmaxf(fmaf(hv[3], c3, f3), 0.f) + bf2f((u16)(xv.y >> 16));
            uint2v o;
            o.x = (unsigned)f2bf(v0) | ((unsigned)f2bf(v1) << 16);
            o.y = (unsigned)f2bf(v2) | ((unsigned)f2bf(v3) << 16);
            __builtin_nontemporal_store(o, (uint2v*)out + i);
        }
    } else {
        for (int i = i0; i < total4; i += stride) {
            floatx4 hv = __builtin_nontemporal_load((const floatx4*)h + i);
            floatx4 xv = __builtin_nontemporal_load((const floatx4*)x + i);
            floatx4 o;
            o[0] = fmaxf(fmaf(hv[0], c0, f0), 0.f) + xv[0];
            o[1] = fmaxf(fmaf(hv[1], c1, f1), 0.f) + xv[1];
            o[2] = fmaxf(fmaf(hv[2], c2, f2), 0.f) + xv[2];
            o[3] = fmaxf(fmaf(hv[3], c3, f3), 0.f) + xv[3];
            __builtin_nontemporal_store(o, (floatx4*)out + i);
        }
    }
    // scalar tail (total % 4 != 0 never happens for D=128, kept for safety)
    for (int i = (total4 << 2) + i0; i < total; i += stride) {
        int d = i & 127;
        float v = fmaxf(fmaf(h[i], sc[d], sh[d]), 0.f);
        if (isbf) ((u16*)out)[i] = f2bf(v + bf2f(((const u16*)x)[i]));
        else      ((float*)out)[i] = v + ((const float*)x)[i];
    }
}

extern "C" void kernel_launch(void* const* d_in, const int* in_sizes, int n_in,
                              void* d_out, int out_size, void* d_ws, size_t ws_size,
                              hipStream_t stream) {
    const void* x     = d_in[0];
    const void* W     = d_in[1];
    const void* b     = d_in[2];
    const void* gamma = d_in[3];
    const void* beta  = d_in[4];
    const int*  ei    = (const int*)d_in[5];

    const int N  = in_sizes[0] / DCH;   // 50000
    const int E  = in_sizes[5] / 2;     // 640000
    const int ND = N * DCH;             // 6,400,000
    const int P  = (N + 1023) / 1024;   // scan partials (49)

    char* wsb = (char*)d_ws;
    int*  ws_i = (int*)wsb;

    // layout: ws_i 64B | Wb 32KB | deg[N] | sums[128] | sumsq[128] | rowptr[N+1] | dinv[N] | part[256] | h[ND] | col[E]
    size_t o_wb   = 64;
    size_t o_deg  = o_wb + 32768;
    size_t o_sum  = o_deg + 4 * (size_t)N;
    size_t o_sq   = o_sum + 512;
    size_t o_rp   = o_sq + 512;
    size_t o_dinv = o_rp + 4 * ((size_t)N + 1) + 4;
    size_t o_part = o_dinv + 4 * (size_t)N;
    size_t o_h    = (o_part + 1024 + 255) & ~(size_t)255;
    size_t o_col  = o_h + 4 * (size_t)ND;
    size_t need_csr = o_col + 4 * (size_t)E;

    (void)hipGetLastError();

    if (ws_size >= need_csr && P <= 256) {
        u16*   Wb    = (u16*)(wsb + o_wb);
        int*   deg   = (int*)(wsb + o_deg);
        float* sums  = (float*)(wsb + o_sum);
        float* sumsq = (float*)(wsb + o_sq);
        int*   rowptr= (int*)(wsb + o_rp);
        float* dinv  = (float*)(wsb + o_dinv);
        int*   part  = (int*)(wsb + o_part);
        float* h     = (float*)(wsb + o_h);
        int*   col   = (int*)(wsb + o_col);
        u16*   y     = (u16*)d_out;   // bf16 y in d_out until out_kernel overwrites

        int GB = (N + 63) / 64;            // gemm blocks
        int FB = (E + 255) / 256;          // fillcsr blocks (covers both edge formats)

        // zero ws_i + Wb + deg + sums + sumsq with a KERNEL (R5 lesson: host
        // memset on the capture path was the abort).
        zero_kernel<<<128, 256, 0, stream>>>((float*)wsb, (int)((o_sq + 512) / 4));
        prep_deg_kernel<<<1250, 256, 0, stream>>>(ei, E, (const u16*)x, ws_i,
                                                  W, Wb, deg, N);
        scanA_kernel<<<P, 256, 0, stream>>>(deg, part, N);
        scanC_kernel<<<P, 256, 0, stream>>>(deg, part, rowptr, dinv, N, P);
        fill_gemm_kernel<<<GB + FB, 256, 0, stream>>>(ei, E, ws_i, deg, col,
                                                      x, Wb, dinv, y, N, GB);
        gather_stats_kernel<<<1024, 256, 0, stream>>>(rowptr, col, y, dinv, b, ws_i,
                                                      h, sums, sumsq, N);
        out_kernel<<<2048, 256, 0, stream>>>(h, x, gamma, beta, ws_i, sums, sumsq,
                                             d_out, ND, 1.0f / (float)N);
    } else {
        // R5-proven fallback: ws_i | deg | dinv | sums | sumsq | acc
        int*   deg   = (int*)(wsb + 16);
        float* dinv  = (float*)(wsb + 16 + 4 * (size_t)N);
        float* sums  = (float*)(wsb + 16 + 8 * (size_t)N);
        float* sumsq = sums + DCH;
        float* acc   = sumsq + DCH;
        size_t need = 16 + 8 * (size_t)N + 1024 + 4 * (size_t)ND;
        if (ws_size < need) {
            int mb = (int)(ws_size >> 20); if (mb > 127) mb = 127;
            float v = 2048.f + 16.f * (float)mb;
            unsigned u; __builtin_memcpy(&u, &v, 4);
            paint_kernel<<<1024, 256, 0, stream>>>((u16*)d_out, out_size, u >> 16);
            return;
        }
        detect_kernel<<<1, 256, 0, stream>>>(ei, 2 * E, (const u16*)x, ws_i);
        zero_kernel<<<2048, 256, 0, stream>>>((float*)(wsb + 16), 2 * N + 256 + ND);
        deg_kernel<<<(E + 255) / 256, 256, 0, stream>>>(ei, E, ws_i, deg, N);
        dinv_kernel<<<(N + 255) / 256, 256, 0, stream>>>(deg, dinv, N, ws_i);
        gemm_valu_kernel<<<(N + ROWS - 1) / ROWS, 256, 0, stream>>>(x, W, dinv, ws_i, d_out, N);
        scatter_kernel<<<(E * 32 + 255) / 256, 256, 0, stream>>>(ei, E, ws_i, d_out, acc, N);
        bnstat_kernel<<<240, 256, 0, stream>>>(d_out, acc, dinv, b, ws_i, sums, sumsq, ND);
        out_kernel<<<256, 256, 0, stream>>>(acc, x, gamma, beta, ws_i, sums, sumsq,
                                            d_out, ND, 1.0f / (float)N);
    }

    if (hipGetLastError() != hipSuccess)
        hipMemsetAsync(d_out, 0x42, (size_t)out_size * 2, stream);
}